// Round 7
// baseline (483.666 us; speedup 1.0000x reference)
//
#include <hip/hip_runtime.h>

// SGM min-sum message passing, 4 directions, dense 21x21 label context.
// out = sum_d L_d - 3u.
//
// Path A (ws >= 4*NELEM floats exactly):
//   transpose3: uT[b][s][w][h] from u (84 planes) + ewT overlay planes for
//     dirs 2,3 inside l2t/l3t plane (b*21+20). 4 tiles per block (loop) to
//     fix the 1-float4-per-thread latency-bound profile.
//   sweep7: 11-lane x 2-label groups, 5 tasks/wave (R6 was 21x1, 3 tasks).
//     Rationale (R3/R5/R6): time pinned ~210us across 557-679 MB traffic ->
//     LDS-unit contention on the per-step exchange (8 LDS ops/wave-step x
//     10.7 waves/CU), not HBM. New layout: exchange write = 1 ds_write_b64
//     (2 labels, slot-interleaved: slot 2l=label l, 2l+1=label l+11; label
//     21 dummy held at +1e30), 6 broadcast b128 reads serve 5 tasks, two
//     independent min-trees per lane (ILP=2). Waves 2731->1640.
//     Wave-UNIFORM dir/rev (adjacent blocks = fwd/bwd of same 5 lines for
//     L2 pairing; no divergence; stage col uniform -> low bank conflicts).
//     2-slot register pipeline (R3/R6-proven), 16-step blocks.
//     Stores staged in LDS 32-step windows, flushed as full-line wave
//     stores: dir0->out (raw L), dir1->l1 (L-u), dir2/3->l2t/l3t (L-u,
//     transposed planes). WRITE_SIZE must stay exactly 344064 KB.
//   finish2: out += l1 + T(l2t) + T(l3t), 4 tiles per block (loop).
// Path B fallback (small ws): sequential no-scratch kernels (unchanged).

#define DLBL 21
#define SP 512
#define NB 4
#define SPSP ((long)SP * SP)
#define NELEM ((long)NB * DLBL * SP * SP)   // 22,020,096 floats
#define BIGF 1e30f

// ---- transpose: u planes (0..83) + ewT overlay planes (84..91), 4 tiles ---
__global__ __launch_bounds__(256)
void transpose3_kernel(const float* __restrict__ u, const float* __restrict__ ew,
                       float* __restrict__ uT, float* l2t, float* l3t)
{
    __shared__ float tile[32][36];
    const int plane = blockIdx.z;
    const float* src;
    float* dst;
    if (plane < NB * DLBL) {
        src = u  + (long)plane * SPSP;
        dst = uT + (long)plane * SPSP;
    } else {
        const int q = plane - NB * DLBL;            // q = b*2 + (dir-2)
        const int b = q >> 1, db = q & 1;
        src = ew + (long)(b * 4 + 2 + db) * SPSP;
        dst = (db ? l3t : l2t) + (long)(b * DLBL + 20) * SPSP;  // overlay
    }
    const int x0 = blockIdx.x * 32;
    const int r  = threadIdx.x >> 3;           // 0..31
    const int c4 = (threadIdx.x & 7) * 4;      // 0,4,..,28
#pragma unroll
    for (int it = 0; it < 4; ++it) {
        const int y0 = (blockIdx.y * 4 + it) * 32;
        const float4 v = *(const float4*)&src[(long)(y0 + r) * SP + (x0 + c4)];
        if (it) __syncthreads();               // prior reads of tile done
        *(float4*)&tile[r][c4] = v;
        __syncthreads();
        float4 ov;
        ov.x = tile[c4 + 0][r];
        ov.y = tile[c4 + 1][r];
        ov.z = tile[c4 + 2][r];
        ov.w = tile[c4 + 3][r];
        *(float4*)&dst[(long)(x0 + r) * SP + (y0 + c4)] = ov;
    }
}

// ---------- main sweep (Path A, 11-lane x 2-label, 5 tasks/wave) ----------
__global__ __launch_bounds__(64, 2)
void sweep7(const float* __restrict__ unary, const float* __restrict__ ew,
            const float* __restrict__ Vmat, const float* __restrict__ uT,
            float* __restrict__ out, float* __restrict__ l1,
            float* l2t, float* l3t)
{
    __shared__ float xch[5][28];         // 112 B row stride: b128-aligned,
                                         // distinct banks per group
    __shared__ float stage[5][693];      // [group][label*33 + (t&31)]
    const int lane = threadIdx.x;
    const int gq   = lane / 11;
    const int gc   = (gq > 4) ? 4 : gq;        // lanes 55-63 shadow group 4
    const int l    = lane - gc * 11;           // 0..10 real; 11..19 shadow
    const bool wlane = (lane < 55);

    // wave-uniform task geometry: adjacent blocks = fwd/bwd of same 5 lines
    const int bid   = blockIdx.x;
    const int axis  = (bid >= 820) ? 1 : 0;
    const int local = bid - 820 * axis;
    const int rev   = local & 1;
    const int lineBase = (local >> 1) * 5;
    const int dir   = axis * 2 + rev;
    const float usub = (dir == 0) ? 0.0f : 1.0f;   // dirs 1-3 store L-u

    const int lg   = lineBase + gc;
    const int line = (lg > 2047) ? 2047 : lg;
    const int b    = line >> 9;
    const int p    = line & (SP - 1);

    const int d0  = (l > 20) ? 20 : l;         // shadow lanes clamped
    const int d1  = l + 11;
    const int d1c = (d1 > 20) ? 20 : d1;       // label 21 = dummy

    // V columns in SLOT order: slot k -> label (k&1 ? k/2+11 : k/2)
    float VcA[22], VcB[22];
#pragma unroll
    for (int k = 0; k < 22; ++k) {
        const int lab  = (k & 1) ? ((k >> 1) + 11) : (k >> 1);
        const bool dum = (lab > 20);
        const int labc = dum ? 20 : lab;
        VcA[k] = dum ? 0.0f : Vmat[labc * DLBL + d0];
        VcB[k] = dum ? 0.0f : Vmat[labc * DLBL + d1c];
    }

    const float* ubase = axis ? uT : unary;
    const float4* uA4 = (const float4*)(ubase + (long)(b * DLBL + d0)  * SPSP + (long)p * SP);
    const float4* uB4 = (const float4*)(ubase + (long)(b * DLBL + d1c) * SPSP + (long)p * SP);
    const float* wrow = axis
        ? ((dir == 2 ? l2t : l3t) + (long)(b * DLBL + 20) * SPSP + (long)p * SP)
        : (ew + (long)(b * 4 + dir) * SPSP + (long)p * SP);
    const float4* w4 = (const float4*)wrow;

    const int frow = lane >> 5, fcol = lane & 31;

    float* fb[5]; bool fvalid[5];
    float* dst = (dir == 0) ? out : (dir == 1) ? l1 : (dir == 2) ? l2t : l3t;
#pragma unroll
    for (int gg = 0; gg < 5; ++gg) {
        const int lgg = lineBase + gg;
        fvalid[gg] = (lgg < 2048);
        const int lc = fvalid[gg] ? lgg : 2047;
        fb[gg] = dst + (long)((lc >> 9) * DLBL) * SPSP + (long)(lc & (SP - 1)) * SP
                     + (long)frow * SPSP;
    }

    float4 AU[4], AV[4], AW[4], BU[4], BV[4], BW[4];
    float curA = 0.0f, curB = 0.0f;

#define QIDX(bi, k) (rev ? (127 - 4 * (bi) - (k)) : (4 * (bi) + (k)))

#define LOADBLK(bi, U, V2, W) do {                                          \
    _Pragma("unroll")                                                       \
    for (int k = 0; k < 4; ++k) {                                           \
        const int q_ = QIDX(bi, k);                                         \
        U[k] = uA4[q_]; V2[k] = uB4[q_]; W[k] = w4[q_];                     \
    } } while (0)

#define PROC(bi, U, V2, W, FIRSTB) do {                                     \
    _Pragma("unroll")                                                       \
    for (int k = 0; k < 4; ++k) {                                           \
        const float uaA[4] = {U[k].x,  U[k].y,  U[k].z,  U[k].w};           \
        const float uaB[4] = {V2[k].x, V2[k].y, V2[k].z, V2[k].w};          \
        const float wa[4]  = {W[k].x,  W[k].y,  W[k].z,  W[k].w};           \
        const int q_ = QIDX(bi, k);                                         \
        _Pragma("unroll")                                                   \
        for (int j = 0; j < 4; ++j) {                                       \
            const int   jc  = rev ? 3 - j : j;                              \
            const float uAc = uaA[jc], uBc = uaB[jc], wc = wa[jc];          \
            const int   t   = q_ * 4 + jc;                                  \
            if (wlane) *(float2*)&xch[gc][2 * l] = make_float2(curA, curB); \
            __builtin_amdgcn_wave_barrier();                                \
            float Lp[24];                                                   \
            _Pragma("unroll")                                               \
            for (int qq = 0; qq < 6; ++qq)                                  \
                ((float4*)Lp)[qq] = ((const float4*)(&xch[gc][0]))[qq];     \
            __builtin_amdgcn_wave_barrier();                                \
            float cA_[22], cB_[22];                                         \
            _Pragma("unroll")                                               \
            for (int kk = 0; kk < 22; ++kk) {                               \
                cA_[kk] = fmaf(wc, VcA[kk], Lp[kk]);                        \
                cB_[kk] = fmaf(wc, VcB[kk], Lp[kk]);                        \
            }                                                               \
            float mA[11], mB[11];                                           \
            _Pragma("unroll")                                               \
            for (int kk = 0; kk < 11; ++kk) {                               \
                mA[kk] = fminf(cA_[2*kk], cA_[2*kk+1]);                     \
                mB[kk] = fminf(cB_[2*kk], cB_[2*kk+1]);                     \
            }                                                               \
            const float rA = fminf(fminf(fminf(fminf(mA[0],mA[1]),          \
                fminf(mA[2],mA[3])), fminf(fminf(mA[4],mA[5]),              \
                fminf(mA[6],mA[7]))), fminf(fminf(mA[8],mA[9]), mA[10]));   \
            const float rB = fminf(fminf(fminf(fminf(mB[0],mB[1]),          \
                fminf(mB[2],mB[3])), fminf(fminf(mB[4],mB[5]),              \
                fminf(mB[6],mB[7]))), fminf(fminf(mB[8],mB[9]), mB[10]));   \
            float nvA = uAc + rA, nvB = uBc + rB;                           \
            if ((FIRSTB) && k == 0 && j == 0) { nvA = uAc; nvB = uBc; }     \
            curA = nvA;                                                     \
            curB = (l == 10) ? BIGF : nvB;   /* dummy label 21 never wins */ \
            const int col = t & 31;                                         \
            if (wlane) stage[gc][l * 33 + col] = fmaf(-usub, uAc, curA);    \
            if (wlane && l < 10)                                            \
                stage[gc][(l + 11) * 33 + col] = fmaf(-usub, uBc, curB);    \
        }                                                                   \
    } } while (0)

#define FLW(w_) do {                                                        \
    __builtin_amdgcn_wave_barrier();                                        \
    const int w0 = rev ? (480 - 32 * (w_)) : (32 * (w_));                   \
    _Pragma("unroll")                                                       \
    for (int gg = 0; gg < 5; ++gg) {                                        \
        if (fvalid[gg]) {                                                   \
            float* bp = fb[gg] + w0;                                        \
            _Pragma("unroll")                                               \
            for (int r2 = 0; r2 < 11; ++r2) {                               \
                const int rr = 2 * r2 + frow;                               \
                if (rr < DLBL) bp[fcol] = stage[gg][rr * 33 + fcol];        \
                bp += 2 * SPSP;                                             \
            }                                                               \
        }                                                                   \
    }                                                                       \
    __builtin_amdgcn_wave_barrier();                                        \
} while (0)

    LOADBLK(0, AU, AV, AW);
    for (int m = 0; m < 16; ++m) {
        LOADBLK(2 * m + 1, BU, BV, BW);            // prefetch odd block
        PROC(2 * m, AU, AV, AW, (m == 0));
        if (m < 15) LOADBLK(2 * m + 2, AU, AV, AW); // prefetch next even
        PROC(2 * m + 1, BU, BV, BW, false);
        FLW(m);                                     // 32-step window done
    }

#undef QIDX
#undef LOADBLK
#undef PROC
#undef FLW
}

// -------- finish: out += l1 + T(l2t) + T(l3t), 4 tiles per block ----------
__global__ __launch_bounds__(256)
void finish2_kernel(const float* __restrict__ l1, const float* __restrict__ l2t,
                    const float* __restrict__ l3t, float* __restrict__ out)
{
    __shared__ float t2[32][36], t3[32][36];
    const long pb = (long)blockIdx.z * SPSP;
    const int x0 = blockIdx.x * 32;
    const int r  = threadIdx.x >> 3;           // 0..31
    const int c4 = (threadIdx.x & 7) * 4;      // 0,4,..,28
#pragma unroll
    for (int it = 0; it < 4; ++it) {
        const int y0 = (blockIdx.y * 4 + it) * 32;
        const float4 v2 = *(const float4*)&l2t[pb + (long)(x0 + r) * SP + (y0 + c4)];
        const float4 v3 = *(const float4*)&l3t[pb + (long)(x0 + r) * SP + (y0 + c4)];
        if (it) __syncthreads();
        *(float4*)&t2[r][c4] = v2;
        *(float4*)&t3[r][c4] = v3;
        __syncthreads();
        const long o = pb + (long)(y0 + r) * SP + (x0 + c4);
        const float4 a = *(const float4*)&l1[o];
        float4 ov = *(const float4*)&out[o];
        ov.x += a.x + t2[c4 + 0][r] + t3[c4 + 0][r];
        ov.y += a.y + t2[c4 + 1][r] + t3[c4 + 1][r];
        ov.z += a.z + t2[c4 + 2][r] + t3[c4 + 2][r];
        ov.w += a.w + t2[c4 + 3][r] + t3[c4 + 3][r];
        *(float4*)&out[o] = ov;
    }
}

// ---------------- fallback (Path B): no-scratch sequential sweeps ----------
template<int MODE>   // 1: dir0 store L to out; 2: out += L - u
__global__ __launch_bounds__(64)
void sweep_fb(const float* __restrict__ unary, const float* __restrict__ ew,
              const float* __restrict__ Vmat, float* __restrict__ out,
              int taskBase)
{
    __shared__ float xch[4][24];
    const int lane = threadIdx.x;
    const int g    = lane / DLBL;
    const int s    = lane - g * DLBL;
    int local = blockIdx.x * 3 + (g < 3 ? g : 0);
    const bool valid = (g < 3) && (local < 2048);
    if (local >= 2048) local = 2047;
    const int taskId = taskBase + local;
    const int dir  = taskId >> 11;
    const int line = taskId & 2047;
    const int b = line >> 9, p = line & (SP - 1);
    const int axis = dir >> 1, rev = dir & 1;

    float Vc[DLBL];
#pragma unroll
    for (int j = 0; j < DLBL; ++j) Vc[j] = Vmat[j * DLBL + s];

    const long ustep = axis ? SP : 1;
    const long ubase = (long)(b * DLBL + s) * SPSP + (axis ? (long)p : (long)p * SP);
    const long wbase = (long)(b * 4 + dir) * SPSP + (axis ? (long)p : (long)p * SP);
    const long uoff  = rev ? -ustep : ustep;
    const long ust   = rev ? (long)(SP - 1) * ustep : 0;

    const float* up = unary + ubase + ust;
    const float* wp = ew    + wbase + ust;
    float*       op = out   + ubase + ust;

    float cur = up[0];
    if (valid && MODE == 1) *op = cur;

    float ub0 = up[uoff], ub1 = up[2*uoff], ub2 = up[3*uoff], ub3 = up[4*uoff];
    float wb0 = wp[uoff], wb1 = wp[2*uoff], wb2 = wp[3*uoff], wb3 = wp[4*uoff];
    float ob0 = 0, ob1 = 0, ob2 = 0, ob3 = 0;
    if (MODE == 2) { ob0 = op[uoff]; ob1 = op[2*uoff]; ob2 = op[3*uoff]; ob3 = op[4*uoff]; }
    const float* upf = up + 4 * uoff;
    const float* wpf = wp + 4 * uoff;
    const float* opf = op + 4 * uoff;

    for (int t = 1; t < SP; ++t) {
        const float u_c = ub0, w_c = wb0, o_c = ob0;
        ub0 = ub1; ub1 = ub2; ub2 = ub3;
        wb0 = wb1; wb1 = wb2; wb2 = wb3;
        if (MODE == 2) { ob0 = ob1; ob1 = ob2; ob2 = ob3; }
        const bool adv = (t + 4) < SP;
        upf += adv ? uoff : 0; wpf += adv ? uoff : 0;
        ub3 = *upf; wb3 = *wpf;
        if (MODE == 2) { opf += adv ? uoff : 0; ob3 = *opf; }

        xch[g][s] = cur;
        __builtin_amdgcn_wave_barrier();
        float Lp[24];
#pragma unroll
        for (int q = 0; q < 6; ++q)
            ((float4*)Lp)[q] = ((const float4*)(&xch[g][0]))[q];
        __builtin_amdgcn_wave_barrier();

        float c[DLBL];
#pragma unroll
        for (int j = 0; j < DLBL; ++j) c[j] = fmaf(w_c, Vc[j], Lp[j]);
        float m7[7];
#pragma unroll
        for (int k = 0; k < 7; ++k)
            m7[k] = fminf(fminf(c[3*k], c[3*k+1]), c[3*k+2]);
        const float ma = fminf(fminf(m7[0], m7[1]), m7[2]);
        const float mb = fminf(fminf(m7[3], m7[4]), m7[5]);
        cur = u_c + fminf(fminf(ma, mb), m7[6]);

        op += uoff;
        if (valid) *op = (MODE == 2) ? (o_c + cur - u_c) : cur;
    }
}

extern "C" void kernel_launch(void* const* d_in, const int* in_sizes, int n_in,
                              void* d_out, int out_size, void* d_ws, size_t ws_size,
                              hipStream_t stream) {
    const float* unary = (const float*)d_in[0];   // (4,1,21,512,512) f32
    const float* ew    = (const float*)d_in[1];   // (4,4,512,512)   f32
    const float* Vmat  = (const float*)d_in[2];   // (21,21)         f32
    float* o = (float*)d_out;

    const size_t needA = (size_t)(4 * NELEM) * sizeof(float);   // 352,321,536 B

    if (ws_size >= needA) {
        float* uT  = (float*)d_ws;
        float* l1  = uT + NELEM;
        float* l2t = l1 + NELEM;
        float* l3t = l2t + NELEM;

        transpose3_kernel<<<dim3(16, 4, NB * DLBL + 8), 256, 0, stream>>>(
            unary, ew, uT, l2t, l3t);

        sweep7<<<1640, 64, 0, stream>>>(unary, ew, Vmat, uT,
                                        o, l1, l2t, l3t);

        finish2_kernel<<<dim3(16, 4, NB * DLBL), 256, 0, stream>>>(l1, l2t, l3t, o);
    } else {
        const int grid = (2048 + 2) / 3;          // 683
        sweep_fb<1><<<grid, 64, 0, stream>>>(unary, ew, Vmat, o, 0);
        for (int d = 1; d < 4; ++d)
            sweep_fb<2><<<grid, 64, 0, stream>>>(unary, ew, Vmat, o, d * 2048);
    }
}

// Round 8
// 457.531 us; speedup vs baseline: 1.0571x; 1.0571x over previous
//
#include <hip/hip_runtime.h>

// SGM min-sum message passing, 4 directions, dense 21x21 label context.
// out = sum_d L_d - 3u.
//
// Path A (ws >= 4*NELEM floats exactly):
//   transpose3: uT[b][s][w][h] from u (84 planes) + ewT overlay planes for
//     dirs 2,3 inside l2t/l3t plane (b*21+20); 4 tiles per block (R7: cut
//     aux time 235->188us vs single-tile).
//   sweep8: == R6's sweep6 (210us, at its LDS-issue roofline: ~90 LDS
//     cyc/wave-step x 2731 waves == measured) with one micro-cut: Lp row
//     read = 5x ds_read_b128 + 1x ds_read_b32 (21 floats used; old 6th
//     b128 read 3 dead floats) -> ~8% off the LDS roofline.
//     R7's tpw=5 regression (295us, occ 16.8%) confirmed: fewer waves than
//     ~8/CU exposes the per-step chain; tpw=3 @ 2731 waves is the optimum.
//     21 lanes/task, 3 tasks/wave, dir-paired task map (fwd+bwd of a line
//     adjacent -> L2 share, FETCH ~300MB), 2-slot register pipeline,
//     stores staged in LDS 32-step windows, flushed as full-line wave
//     stores: dir0->out (raw L), dir1->l1 (L-u), dir2/3->l2t/l3t (L-u,
//     transposed planes). WRITE_SIZE must stay exactly 344064 KB.
//   finish2: out += l1 + T(l2t) + T(l3t), 4 tiles per block.
// Path B fallback (small ws): sequential no-scratch kernels (unchanged).

#define DLBL 21
#define SP 512
#define NB 4
#define SPSP ((long)SP * SP)
#define NELEM ((long)NB * DLBL * SP * SP)   // 22,020,096 floats

__device__ __forceinline__ void map_task(int i, int& dir, int& line)
{
    if (i < 4096) { dir = i & 1;       line = i >> 1; }
    else          { const int j = i - 4096; dir = 2 + (j & 1); line = j >> 1; }
}

// ---- transpose: u planes (0..83) + ewT overlay planes (84..91), 4 tiles ---
__global__ __launch_bounds__(256)
void transpose3_kernel(const float* __restrict__ u, const float* __restrict__ ew,
                       float* __restrict__ uT, float* l2t, float* l3t)
{
    __shared__ float tile[32][36];
    const int plane = blockIdx.z;
    const float* src;
    float* dst;
    if (plane < NB * DLBL) {
        src = u  + (long)plane * SPSP;
        dst = uT + (long)plane * SPSP;
    } else {
        const int q = plane - NB * DLBL;            // q = b*2 + (dir-2)
        const int b = q >> 1, db = q & 1;
        src = ew + (long)(b * 4 + 2 + db) * SPSP;
        dst = (db ? l3t : l2t) + (long)(b * DLBL + 20) * SPSP;  // overlay
    }
    const int x0 = blockIdx.x * 32;
    const int r  = threadIdx.x >> 3;           // 0..31
    const int c4 = (threadIdx.x & 7) * 4;      // 0,4,..,28
#pragma unroll
    for (int it = 0; it < 4; ++it) {
        const int y0 = (blockIdx.y * 4 + it) * 32;
        const float4 v = *(const float4*)&src[(long)(y0 + r) * SP + (x0 + c4)];
        if (it) __syncthreads();               // prior reads of tile done
        *(float4*)&tile[r][c4] = v;
        __syncthreads();
        float4 ov;
        ov.x = tile[c4 + 0][r];
        ov.y = tile[c4 + 1][r];
        ov.z = tile[c4 + 2][r];
        ov.w = tile[c4 + 3][r];
        *(float4*)&dst[(long)(x0 + r) * SP + (y0 + c4)] = ov;
    }
}

// ------------- main sweep (Path A, 2-slot pipeline + paired map) -----------
__global__ __launch_bounds__(64, 3)
void sweep8(const float* __restrict__ unary, const float* __restrict__ ew,
            const float* __restrict__ Vmat, const float* __restrict__ uT,
            float* __restrict__ out, float* __restrict__ l1,
            float* l2t, float* l3t)
{
    __shared__ float xch[4][24];
    __shared__ float stage[4][693];      // [group][s*33 + (t&31)], +1 pad/row
    const int lane = threadIdx.x;
    const int g    = lane / DLBL;              // 0..2 (3 = idle lane 63)
    const int s    = lane - g * DLBL;
    int taskId = blockIdx.x * 3 + (g < 3 ? g : 0);
    if (taskId >= 8192) taskId = 8191;

    int dir, line;
    map_task(taskId, dir, line);
    const int b    = line >> 9;
    const int p    = line & (SP - 1);          // h for axis 0, w for axis 1
    const int axis = dir >> 1;
    const int rev  = dir & 1;
    const float usub = (dir == 0) ? 0.0f : 1.0f;   // dirs 1-3 store L-u

    float Vc[DLBL];
#pragma unroll
    for (int j = 0; j < DLBL; ++j) Vc[j] = Vmat[j * DLBL + s];

    const float4* ub4 = (const float4*)((axis ? uT : unary)
                        + (long)(b * DLBL + s) * SPSP + (long)p * SP);
    // w stream: stride-1 everywhere (ewT overlay planes for vertical dirs)
    const float* wbase = axis
        ? ((dir == 2 ? l2t : l3t) + (long)(b * DLBL + 20) * SPSP + (long)p * SP)
        : (ew + (long)(b * 4 + dir) * SPSP + (long)p * SP);
    const float4* wb4 = (const float4*)wbase;

    const int frow = lane >> 5, fcol = lane & 31;
    const int stbase = s * 33;

    // flush per-task constants, hoisted out of the loop
    float* fb[3]; int wrev[3]; bool fvalid[3];
#pragma unroll
    for (int gg = 0; gg < 3; ++gg) {
        const int tid = blockIdx.x * 3 + gg;
        fvalid[gg] = (tid < 8192);
        int d_, ln;
        map_task(fvalid[gg] ? tid : 8191, d_, ln);
        const int bb = ln >> 9;
        const int pp = ln & (SP - 1);
        wrev[gg] = d_ & 1;
        float* dst = (d_ == 0) ? out : (d_ == 1) ? l1 : (d_ == 2) ? l2t : l3t;
        fb[gg] = dst + (long)(bb * DLBL) * SPSP + (long)pp * SP + (long)frow * SPSP;
    }

    float4 uA[4], uB[4], wA[4], wB[4];
    float cur = 0.0f;

#define QIDX(bi, k) (rev ? (127 - 4 * (bi) - (k)) : (4 * (bi) + (k)))

#define LOADBLK(bi, U, W) do {                                              \
    _Pragma("unroll")                                                       \
    for (int k = 0; k < 4; ++k) {                                           \
        const int q_ = QIDX(bi, k);                                         \
        U[k] = ub4[q_]; W[k] = wb4[q_];                                     \
    } } while (0)

#define PROC(bi, U, W, FIRSTB) do {                                         \
    _Pragma("unroll")                                                       \
    for (int k = 0; k < 4; ++k) {                                           \
        const float ua_[4] = {U[k].x, U[k].y, U[k].z, U[k].w};              \
        const float wa_[4] = {W[k].x, W[k].y, W[k].z, W[k].w};              \
        const int q_ = QIDX(bi, k);                                         \
        _Pragma("unroll")                                                   \
        for (int j = 0; j < 4; ++j) {                                       \
            const int   jc  = rev ? 3 - j : j;                              \
            const float u_c = ua_[jc];                                      \
            const float w_c = wa_[jc];                                      \
            const int   t   = q_ * 4 + jc;                                  \
            xch[g][s] = cur;                                                \
            __builtin_amdgcn_wave_barrier();                                \
            float Lp[21];                                                   \
            _Pragma("unroll")                                               \
            for (int qq = 0; qq < 5; ++qq)                                  \
                ((float4*)Lp)[qq] = ((const float4*)(&xch[g][0]))[qq];      \
            Lp[20] = xch[g][20];                                            \
            __builtin_amdgcn_wave_barrier();                                \
            float c[DLBL];                                                  \
            _Pragma("unroll")                                               \
            for (int jj = 0; jj < DLBL; ++jj)                               \
                c[jj] = fmaf(w_c, Vc[jj], Lp[jj]);                          \
            float m7[7];                                                    \
            _Pragma("unroll")                                               \
            for (int kk = 0; kk < 7; ++kk)                                  \
                m7[kk] = fminf(fminf(c[3*kk], c[3*kk+1]), c[3*kk+2]);       \
            const float ma = fminf(fminf(m7[0], m7[1]), m7[2]);             \
            const float mb = fminf(fminf(m7[3], m7[4]), m7[5]);             \
            const float nv = u_c + fminf(fminf(ma, mb), m7[6]);             \
            cur = ((FIRSTB) && k == 0 && j == 0) ? u_c : nv;                \
            stage[g][stbase + (t & 31)] = fmaf(-usub, u_c, cur);            \
        }                                                                   \
    } } while (0)

#define FLW(w_) do {                                                        \
    __builtin_amdgcn_wave_barrier();                                        \
    _Pragma("unroll")                                                       \
    for (int gg = 0; gg < 3; ++gg) {                                        \
        if (fvalid[gg]) {                                                   \
            float* bp = fb[gg] + (wrev[gg] ? (480 - 32 * (w_))              \
                                           : (32 * (w_)));                  \
            _Pragma("unroll")                                               \
            for (int r2 = 0; r2 < 11; ++r2) {                               \
                const int rr = 2 * r2 + frow;                               \
                if (rr < DLBL) bp[fcol] = stage[gg][rr * 33 + fcol];        \
                bp += 2 * SPSP;                                             \
            }                                                               \
        }                                                                   \
    }                                                                       \
    __builtin_amdgcn_wave_barrier();                                        \
} while (0)

    LOADBLK(0, uA, wA);
    for (int m = 0; m < 16; ++m) {
        LOADBLK(2 * m + 1, uB, wB);            // prefetch odd block
        PROC(2 * m, uA, wA, (m == 0));
        if (m < 15) LOADBLK(2 * m + 2, uA, wA);   // prefetch next even block
        PROC(2 * m + 1, uB, wB, false);
        FLW(m);                                // 32-step window complete
    }

#undef QIDX
#undef LOADBLK
#undef PROC
#undef FLW
}

// -------- finish: out += l1 + T(l2t) + T(l3t), 4 tiles per block ----------
__global__ __launch_bounds__(256)
void finish2_kernel(const float* __restrict__ l1, const float* __restrict__ l2t,
                    const float* __restrict__ l3t, float* __restrict__ out)
{
    __shared__ float t2[32][36], t3[32][36];
    const long pb = (long)blockIdx.z * SPSP;
    const int x0 = blockIdx.x * 32;
    const int r  = threadIdx.x >> 3;           // 0..31
    const int c4 = (threadIdx.x & 7) * 4;      // 0,4,..,28
#pragma unroll
    for (int it = 0; it < 4; ++it) {
        const int y0 = (blockIdx.y * 4 + it) * 32;
        const float4 v2 = *(const float4*)&l2t[pb + (long)(x0 + r) * SP + (y0 + c4)];
        const float4 v3 = *(const float4*)&l3t[pb + (long)(x0 + r) * SP + (y0 + c4)];
        if (it) __syncthreads();
        *(float4*)&t2[r][c4] = v2;
        *(float4*)&t3[r][c4] = v3;
        __syncthreads();
        const long o = pb + (long)(y0 + r) * SP + (x0 + c4);
        const float4 a = *(const float4*)&l1[o];
        float4 ov = *(const float4*)&out[o];
        ov.x += a.x + t2[c4 + 0][r] + t3[c4 + 0][r];
        ov.y += a.y + t2[c4 + 1][r] + t3[c4 + 1][r];
        ov.z += a.z + t2[c4 + 2][r] + t3[c4 + 2][r];
        ov.w += a.w + t2[c4 + 3][r] + t3[c4 + 3][r];
        *(float4*)&out[o] = ov;
    }
}

// ---------------- fallback (Path B): no-scratch sequential sweeps ----------
template<int MODE>   // 1: dir0 store L to out; 2: out += L - u
__global__ __launch_bounds__(64)
void sweep_fb(const float* __restrict__ unary, const float* __restrict__ ew,
              const float* __restrict__ Vmat, float* __restrict__ out,
              int taskBase)
{
    __shared__ float xch[4][24];
    const int lane = threadIdx.x;
    const int g    = lane / DLBL;
    const int s    = lane - g * DLBL;
    int local = blockIdx.x * 3 + (g < 3 ? g : 0);
    const bool valid = (g < 3) && (local < 2048);
    if (local >= 2048) local = 2047;
    const int taskId = taskBase + local;
    const int dir  = taskId >> 11;
    const int line = taskId & 2047;
    const int b = line >> 9, p = line & (SP - 1);
    const int axis = dir >> 1, rev = dir & 1;

    float Vc[DLBL];
#pragma unroll
    for (int j = 0; j < DLBL; ++j) Vc[j] = Vmat[j * DLBL + s];

    const long ustep = axis ? SP : 1;
    const long ubase = (long)(b * DLBL + s) * SPSP + (axis ? (long)p : (long)p * SP);
    const long wbase = (long)(b * 4 + dir) * SPSP + (axis ? (long)p : (long)p * SP);
    const long uoff  = rev ? -ustep : ustep;
    const long ust   = rev ? (long)(SP - 1) * ustep : 0;

    const float* up = unary + ubase + ust;
    const float* wp = ew    + wbase + ust;
    float*       op = out   + ubase + ust;

    float cur = up[0];
    if (valid && MODE == 1) *op = cur;

    float ub0 = up[uoff], ub1 = up[2*uoff], ub2 = up[3*uoff], ub3 = up[4*uoff];
    float wb0 = wp[uoff], wb1 = wp[2*uoff], wb2 = wp[3*uoff], wb3 = wp[4*uoff];
    float ob0 = 0, ob1 = 0, ob2 = 0, ob3 = 0;
    if (MODE == 2) { ob0 = op[uoff]; ob1 = op[2*uoff]; ob2 = op[3*uoff]; ob3 = op[4*uoff]; }
    const float* upf = up + 4 * uoff;
    const float* wpf = wp + 4 * uoff;
    const float* opf = op + 4 * uoff;

    for (int t = 1; t < SP; ++t) {
        const float u_c = ub0, w_c = wb0, o_c = ob0;
        ub0 = ub1; ub1 = ub2; ub2 = ub3;
        wb0 = wb1; wb1 = wb2; wb2 = wb3;
        if (MODE == 2) { ob0 = ob1; ob1 = ob2; ob2 = ob3; }
        const bool adv = (t + 4) < SP;
        upf += adv ? uoff : 0; wpf += adv ? uoff : 0;
        ub3 = *upf; wb3 = *wpf;
        if (MODE == 2) { opf += adv ? uoff : 0; ob3 = *opf; }

        xch[g][s] = cur;
        __builtin_amdgcn_wave_barrier();
        float Lp[24];
#pragma unroll
        for (int q = 0; q < 6; ++q)
            ((float4*)Lp)[q] = ((const float4*)(&xch[g][0]))[q];
        __builtin_amdgcn_wave_barrier();

        float c[DLBL];
#pragma unroll
        for (int j = 0; j < DLBL; ++j) c[j] = fmaf(w_c, Vc[j], Lp[j]);
        float m7[7];
#pragma unroll
        for (int k = 0; k < 7; ++k)
            m7[k] = fminf(fminf(c[3*k], c[3*k+1]), c[3*k+2]);
        const float ma = fminf(fminf(m7[0], m7[1]), m7[2]);
        const float mb = fminf(fminf(m7[3], m7[4]), m7[5]);
        cur = u_c + fminf(fminf(ma, mb), m7[6]);

        op += uoff;
        if (valid) *op = (MODE == 2) ? (o_c + cur - u_c) : cur;
    }
}

extern "C" void kernel_launch(void* const* d_in, const int* in_sizes, int n_in,
                              void* d_out, int out_size, void* d_ws, size_t ws_size,
                              hipStream_t stream) {
    const float* unary = (const float*)d_in[0];   // (4,1,21,512,512) f32
    const float* ew    = (const float*)d_in[1];   // (4,4,512,512)   f32
    const float* Vmat  = (const float*)d_in[2];   // (21,21)         f32
    float* o = (float*)d_out;

    const size_t needA = (size_t)(4 * NELEM) * sizeof(float);   // 352,321,536 B

    if (ws_size >= needA) {
        float* uT  = (float*)d_ws;
        float* l1  = uT + NELEM;
        float* l2t = l1 + NELEM;
        float* l3t = l2t + NELEM;

        transpose3_kernel<<<dim3(16, 4, NB * DLBL + 8), 256, 0, stream>>>(
            unary, ew, uT, l2t, l3t);

        const int grid = (8192 + 2) / 3;          // 2731
        sweep8<<<grid, 64, 0, stream>>>(unary, ew, Vmat, uT,
                                        o, l1, l2t, l3t);

        finish2_kernel<<<dim3(16, 4, NB * DLBL), 256, 0, stream>>>(l1, l2t, l3t, o);
    } else {
        const int grid = (2048 + 2) / 3;          // 683
        sweep_fb<1><<<grid, 64, 0, stream>>>(unary, ew, Vmat, o, 0);
        for (int d = 1; d < 4; ++d)
            sweep_fb<2><<<grid, 64, 0, stream>>>(unary, ew, Vmat, o, d * 2048);
    }
}